// Round 1
// baseline (537.704 us; speedup 1.0000x reference)
//
#include <hip/hip_runtime.h>
#include <hip/hip_bf16.h>
#include <math.h>

typedef __bf16 bf16x8 __attribute__((ext_vector_type(8)));
typedef float  f32x4  __attribute__((ext_vector_type(4)));

#define LH 264   // Hs row stride in bf16 elems: 256 + 8 (16B-aligned rows, 2-way-max bank alias)

// ---------------- Direct conv 3x3 stride2 pad1 + BN(scale,bias) + ReLU ----------------
// One thread per (n, oy, ox), computes all 24 output channels. Weights HWIO in LDS.
template<int CIN>
__global__ void conv_bn_relu(const float* __restrict__ x, const float* __restrict__ w,
                             const float* __restrict__ sc, const float* __restrict__ bi,
                             float* __restrict__ y, int N, int H, int W) {
  const int OH = H >> 1, OW = W >> 1;
  __shared__ float wl[9 * CIN * 24];
  __shared__ float scl[24], bil[24];
  for (int i = threadIdx.x; i < 9 * CIN * 24; i += blockDim.x) wl[i] = w[i];
  if (threadIdx.x < 24) { scl[threadIdx.x] = sc[threadIdx.x]; bil[threadIdx.x] = bi[threadIdx.x]; }
  __syncthreads();

  int idx = blockIdx.x * blockDim.x + threadIdx.x;
  int total = N * OH * OW;
  if (idx >= total) return;
  int ox = idx % OW; int t = idx / OW; int oy = t % OH; int n = t / OH;

  float acc[24];
#pragma unroll
  for (int co = 0; co < 24; ++co) acc[co] = 0.f;

  for (int ci = 0; ci < CIN; ++ci) {
    const float* xp = x + (size_t)(n * CIN + ci) * H * W;
#pragma unroll
    for (int ky = 0; ky < 3; ++ky) {
      int iy = 2 * oy + ky - 1;
      if (iy < 0 || iy >= H) continue;
#pragma unroll
      for (int kx = 0; kx < 3; ++kx) {
        int ix = 2 * ox + kx - 1;
        if (ix < 0 || ix >= W) continue;
        float v = xp[iy * W + ix];
        const float* wp = &wl[((ky * 3 + kx) * CIN + ci) * 24];
#pragma unroll
        for (int co = 0; co < 24; ++co) acc[co] += v * wp[co];
      }
    }
  }
  float* yp = y + (size_t)n * 24 * OH * OW + oy * OW + ox;
#pragma unroll
  for (int co = 0; co < 24; ++co)
    yp[(size_t)co * OH * OW] = fmaxf(acc[co] * scl[co] + bil[co], 0.f);
}

// ---------------- Transpose+convert g_w2/3/4 (256x256 fp32, [k][n]) -> Wt bf16 [l][n][k] ----------------
__global__ void wt_convert(const float* __restrict__ g2, const float* __restrict__ g3,
                           const float* __restrict__ g4, __bf16* __restrict__ Wt) {
  int idx = blockIdx.x * 256 + threadIdx.x;   // l*65536 + n*256 + k
  int l = idx >> 16; int r = (idx >> 8) & 255; int k = idx & 255;
  const float* src = (l == 0) ? g2 : (l == 1) ? g3 : g4;
  Wt[idx] = (__bf16)src[k * 256 + r];
}

// ---------------- x_feat (24 conv ch + 2 pos) @ W1a / W1b -> hi, hj  (fp32) ----------------
__global__ void embed_hij(const float* __restrict__ c3, const float* __restrict__ gw1,
                          float* __restrict__ hi, float* __restrict__ hj) {
  int nb = blockIdx.x;               // n*64 + p
  int n = nb >> 6, p = nb & 63;
  int py = p >> 3, px = p & 7;
  int t = threadIdx.x;
  __shared__ float xf[26];
  if (t < 24)       xf[t]  = c3[((size_t)(n * 24 + t) * 8 + py) * 8 + px];
  else if (t == 24) xf[24] = -1.f + (2.f / 7.f) * px;  // cx: varies with x
  else if (t == 25) xf[25] = -1.f + (2.f / 7.f) * py;  // cy: varies with y
  __syncthreads();
  float a = 0.f, b = 0.f;
#pragma unroll
  for (int c = 0; c < 26; ++c) {
    float v = xf[c];
    a += v * gw1[c * 256 + t];          // W1a = g_w1[0:26]
    b += v * gw1[(26 + c) * 256 + t];   // W1b = g_w1[26:52]
  }
  hi[(size_t)nb * 256 + t] = a;
  hj[(size_t)nb * 256 + t] = b;
}

// ---------------- hq = qst @ W1c + g_b1 ----------------
__global__ void hq_kernel(const float* __restrict__ qst, const float* __restrict__ gw1,
                          const float* __restrict__ gb1, float* __restrict__ hq) {
  int n = blockIdx.x, t = threadIdx.x;
  __shared__ float qs[128];
  if (t < 128) qs[t] = qst[n * 128 + t];
  __syncthreads();
  float a = gb1[t];
  for (int c = 0; c < 128; ++c) a += qs[c] * gw1[(52 + c) * 256 + t];  // W1c = g_w1[52:180]
  hq[n * 256 + t] = a;
}

// ---------------- Fused relation network: one WG per (n, i); 64 j-rows x 256 feat ----------------
// h1 = relu(hj[j] + hi[i] + hq) staged bf16 in LDS; 3 chained 256x256 bf16 MFMA layers;
// final layer reduced over rows -> atomicAdd into s[n][col].
__global__ void g_fused(const float* __restrict__ hi, const float* __restrict__ hj,
                        const float* __restrict__ hq, const __bf16* __restrict__ Wt,
                        const float* __restrict__ b2, const float* __restrict__ b3,
                        const float* __restrict__ b4, float* __restrict__ s_out) {
  const int nb = blockIdx.x;
  const int n = nb >> 6;
  const int tid = threadIdx.x;
  const int wave = tid >> 6, lane = tid & 63;
  const int q = lane >> 4, lr = lane & 15;

  __shared__ __align__(16) __bf16 Hs[64 * LH];
  __shared__ float hiq[256];

  hiq[tid] = hi[(size_t)nb * 256 + tid] + hq[n * 256 + tid];
  __syncthreads();

  // Build H1 = relu(hj_block + hiq), bf16 into LDS
  const float* hjb = hj + (size_t)n * 64 * 256;
#pragma unroll
  for (int it = 0; it < 16; ++it) {
    int flat = it * 1024 + tid * 4;            // j*256 + c
    int j = flat >> 8, c = flat & 255;
    float4 v = *(const float4*)(hjb + flat);
    __bf16* d = &Hs[j * LH + c];
    d[0] = (__bf16)fmaxf(v.x + hiq[c],     0.f);
    d[1] = (__bf16)fmaxf(v.y + hiq[c + 1], 0.f);
    d[2] = (__bf16)fmaxf(v.z + hiq[c + 2], 0.f);
    d[3] = (__bf16)fmaxf(v.w + hiq[c + 3], 0.f);
  }
  __syncthreads();

  const int colloc = wave * 64 + lr;   // + c*16 per col-tile

  for (int l = 0; l < 3; ++l) {
    const __bf16* Wl = Wt + (size_t)l * 65536;
    const float* bl = (l == 0) ? b2 : (l == 1) ? b3 : b4;

    f32x4 acc[4][4];
#pragma unroll
    for (int r = 0; r < 4; ++r)
#pragma unroll
      for (int c = 0; c < 4; ++c) acc[r][c] = (f32x4){0.f, 0.f, 0.f, 0.f};

    for (int k0 = 0; k0 < 256; k0 += 32) {
      bf16x8 a[4], b[4];
#pragma unroll
      for (int r = 0; r < 4; ++r)
        a[r] = *(const bf16x8*)&Hs[(r * 16 + lr) * LH + k0 + q * 8];
#pragma unroll
      for (int c = 0; c < 4; ++c)
        b[c] = *(const bf16x8*)&Wl[(size_t)(colloc + c * 16) * 256 + k0 + q * 8];
#pragma unroll
      for (int r = 0; r < 4; ++r)
#pragma unroll
        for (int c = 0; c < 4; ++c)
          acc[r][c] = __builtin_amdgcn_mfma_f32_16x16x32_bf16(a[r], b[c], acc[r][c], 0, 0, 0);
    }

    float bias[4];
#pragma unroll
    for (int c = 0; c < 4; ++c) bias[c] = bl[colloc + c * 16];

    if (l < 2) {
      __syncthreads();   // all waves done reading Hs
#pragma unroll
      for (int r = 0; r < 4; ++r)
#pragma unroll
        for (int c = 0; c < 4; ++c)
#pragma unroll
          for (int reg = 0; reg < 4; ++reg) {
            int row = r * 16 + q * 4 + reg;    // C/D: row = quad*4 + reg
            Hs[row * LH + colloc + c * 16] = (__bf16)fmaxf(acc[r][c][reg] + bias[c], 0.f);
          }
      __syncthreads();
    } else {
      // final layer: relu + column-sum over all 64 rows, then atomicAdd
#pragma unroll
      for (int c = 0; c < 4; ++c) {
        float cs = 0.f;
#pragma unroll
        for (int r = 0; r < 4; ++r)
#pragma unroll
          for (int reg = 0; reg < 4; ++reg)
            cs += fmaxf(acc[r][c][reg] + bias[c], 0.f);
        cs += __shfl_xor(cs, 16);
        cs += __shfl_xor(cs, 32);
        if (q == 0) atomicAdd(&s_out[n * 256 + colloc + c * 16], cs);
      }
    }
  }
}

// ---------------- f-network + classifier + log_softmax: one WG per batch row ----------------
__global__ void f_net(const float* __restrict__ s, const float* __restrict__ fw1,
                      const float* __restrict__ fb1, const float* __restrict__ fw2,
                      const float* __restrict__ fb2, const float* __restrict__ cw,
                      const float* __restrict__ cb, float* __restrict__ out) {
  int n = blockIdx.x, t = threadIdx.x;
  __shared__ float buf[256], buf2[256], zs[32];
  buf[t] = s[n * 256 + t];
  __syncthreads();
  float a = fb1[t];
  for (int c = 0; c < 256; ++c) a += buf[c] * fw1[c * 256 + t];
  a = fmaxf(a, 0.f);
  buf2[t] = a;
  __syncthreads();
  float y = fb2[t];
  for (int c = 0; c < 256; ++c) y += buf2[c] * fw2[c * 256 + t];
  y = fmaxf(y, 0.f);
  __syncthreads();
  buf[t] = y;
  __syncthreads();
  float z = 0.f;
  if (t < 32) {
    z = cb[t];
    for (int c = 0; c < 256; ++c) z += buf[c] * cw[c * 32 + t];
    zs[t] = z;
  }
  __syncthreads();
  if (t < 32) {
    float m = -1e30f;
    for (int c = 0; c < 32; ++c) m = fmaxf(m, zs[c]);
    float se = 0.f;
    for (int c = 0; c < 32; ++c) se += expf(zs[c] - m);
    out[n * 32 + t] = z - m - logf(se);
  }
}

extern "C" void kernel_launch(void* const* d_in, const int* in_sizes, int n_in,
                              void* d_out, int out_size, void* d_ws, size_t ws_size,
                              hipStream_t stream) {
  const float* img  = (const float*)d_in[0];
  const float* qst  = (const float*)d_in[1];
  const float* w0   = (const float*)d_in[2];
  const float* w1   = (const float*)d_in[3];
  const float* w2   = (const float*)d_in[4];
  const float* w3   = (const float*)d_in[5];
  const float* bs0  = (const float*)d_in[6];
  const float* bb0  = (const float*)d_in[7];
  const float* bs1  = (const float*)d_in[8];
  const float* bb1  = (const float*)d_in[9];
  const float* bs2  = (const float*)d_in[10];
  const float* bb2  = (const float*)d_in[11];
  const float* bs3  = (const float*)d_in[12];
  const float* bb3  = (const float*)d_in[13];
  const float* gw1  = (const float*)d_in[14];
  const float* gb1  = (const float*)d_in[15];
  const float* gw2  = (const float*)d_in[16];
  const float* gb2  = (const float*)d_in[17];
  const float* gw3  = (const float*)d_in[18];
  const float* gb3  = (const float*)d_in[19];
  const float* gw4  = (const float*)d_in[20];
  const float* gb4  = (const float*)d_in[21];
  const float* fw1  = (const float*)d_in[22];
  const float* fb1  = (const float*)d_in[23];
  const float* fw2  = (const float*)d_in[24];
  const float* fb2  = (const float*)d_in[25];
  const float* cw   = (const float*)d_in[26];
  const float* cb   = (const float*)d_in[27];

  char* ws = (char*)d_ws;
  // conv activations
  float* c0 = (float*)(ws + 0);                    // 64*24*64*64 f32 = 25,165,824 B
  float* c1 = (float*)(ws + 25165824);             //  6,291,456 B
  float* c2 = (float*)(ws + 31457280);             //  1,572,864 B
  float* c3 = (float*)(ws + 33030144);             //    393,216 B  (total 33,423,360 B)
  // reuse c0's region after conv1 has consumed it (stream-ordered):
  float*  hi = (float*)(ws + 0);                   // 4,194,304 B
  float*  hj = (float*)(ws + 4194304);             // 4,194,304 B
  float*  hqb = (float*)(ws + 8388608);            //    65,536 B
  float*  sbuf = (float*)(ws + 8454144);           //    65,536 B
  __bf16* Wt = (__bf16*)(ws + 8519680);            //   393,216 B (< 25 MB, inside c0 region)

  conv_bn_relu<3><<<1024, 256, 0, stream>>>(img, w0, bs0, bb0, c0, 64, 128, 128);
  conv_bn_relu<24><<<256, 256, 0, stream>>>(c0, w1, bs1, bb1, c1, 64, 64, 64);
  conv_bn_relu<24><<<64, 256, 0, stream>>>(c1, w2, bs2, bb2, c2, 64, 32, 32);
  conv_bn_relu<24><<<16, 256, 0, stream>>>(c2, w3, bs3, bb3, c3, 64, 16, 16);

  // From here on the c0 region is dead; safe to overwrite.
  wt_convert<<<768, 256, 0, stream>>>(gw2, gw3, gw4, Wt);
  embed_hij<<<4096, 256, 0, stream>>>(c3, gw1, hi, hj);
  hq_kernel<<<64, 256, 0, stream>>>(qst, gw1, gb1, hqb);

  hipMemsetAsync(sbuf, 0, 64 * 256 * sizeof(float), stream);
  g_fused<<<4096, 256, 0, stream>>>(hi, hj, hqb, Wt, gb2, gb3, gb4, sbuf);
  f_net<<<64, 256, 0, stream>>>(sbuf, fw1, fb1, fw2, fb2, cw, cb, (float*)d_out);
}

// Round 2
// 487.135 us; speedup vs baseline: 1.1038x; 1.1038x over previous
//
#include <hip/hip_runtime.h>
#include <hip/hip_bf16.h>
#include <math.h>

typedef __bf16 bf16x8 __attribute__((ext_vector_type(8)));
typedef __bf16 bf16x4 __attribute__((ext_vector_type(4)));
typedef float  f32x4  __attribute__((ext_vector_type(4)));

#define LH 264   // Hs row stride in bf16 elems (528 B): breaks power-of-2 bank aliasing

// ---------------- Direct conv 3x3 stride2 pad1 + BN(scale,bias) + ReLU ----------------
// One thread per (n, oy, ox), computes all 24 output channels.
// STAGE=true: weights staged in LDS (for 256-thread blocks).
// STAGE=false: weights read directly (uniform index -> scalar loads; for 64-thread blocks).
template<int CIN, bool STAGE>
__global__ void conv_bn_relu(const float* __restrict__ x, const float* __restrict__ w,
                             const float* __restrict__ sc, const float* __restrict__ bi,
                             float* __restrict__ y, int N, int H, int W) {
  const int OH = H >> 1, OW = W >> 1;
  __shared__ float wl[STAGE ? 9 * CIN * 24 : 1];
  if (STAGE) {
    for (int i = threadIdx.x; i < 9 * CIN * 24; i += blockDim.x) wl[i] = w[i];
    __syncthreads();
  }
  const float* wsrc = STAGE ? wl : w;

  int idx = blockIdx.x * blockDim.x + threadIdx.x;
  int total = N * OH * OW;
  if (idx >= total) return;
  int ox = idx % OW; int t = idx / OW; int oy = t % OH; int n = t / OH;

  float acc[24];
#pragma unroll
  for (int co = 0; co < 24; ++co) acc[co] = 0.f;

  for (int ci = 0; ci < CIN; ++ci) {
    const float* xp = x + (size_t)(n * CIN + ci) * H * W;
#pragma unroll
    for (int ky = 0; ky < 3; ++ky) {
      int iy = 2 * oy + ky - 1;
      if (iy < 0 || iy >= H) continue;
#pragma unroll
      for (int kx = 0; kx < 3; ++kx) {
        int ix = 2 * ox + kx - 1;
        if (ix < 0 || ix >= W) continue;
        float v = xp[iy * W + ix];
        const float* wp = &wsrc[((ky * 3 + kx) * CIN + ci) * 24];
#pragma unroll
        for (int co = 0; co < 24; ++co) acc[co] += v * wp[co];
      }
    }
  }
  float* yp = y + (size_t)n * 24 * OH * OW + oy * OW + ox;
#pragma unroll
  for (int co = 0; co < 24; ++co)
    yp[(size_t)co * OH * OW] = fmaxf(acc[co] * sc[co] + bi[co], 0.f);
}

// ---------------- g_w2/3/4 (256x256 fp32 [k][n]) -> Wfrag bf16 in MFMA-B-fragment order -----
// Layout: elem((l, ks, n, q, j)) at ((l*8+ks)*256 + n)*32 + q*8 + j,
// holding source src[k = ks*32 + q*8 + j][n].  A wave loading (q=lane>>4, lr=lane&15)
// with n = base+lr reads 64 x 16B covering 1024 contiguous bytes -> fully coalesced.
__global__ void wt_frag(const float* __restrict__ g2, const float* __restrict__ g3,
                        const float* __restrict__ g4, __bf16* __restrict__ Wt) {
  int l = blockIdx.x >> 3, ks = blockIdx.x & 7;
  const float* src = (l == 0) ? g2 : (l == 1) ? g3 : g4;
  __shared__ float tile[32][257];
  int t = threadIdx.x;
  for (int kk = 0; kk < 32; ++kk) tile[kk][t] = src[(ks * 32 + kk) * 256 + t];
  __syncthreads();
  int q = t & 3, nb = t >> 2;
  __bf16* out = Wt + (size_t)(l * 8 + ks) * 8192;
#pragma unroll
  for (int i = 0; i < 4; ++i) {
    int n = i * 64 + nb;
    bf16x8 v;
#pragma unroll
    for (int j = 0; j < 8; ++j) v[j] = (__bf16)tile[q * 8 + j][n];
    *(bf16x8*)&out[n * 32 + q * 8] = v;
  }
}

// ---------------- x_feat (24 conv ch + 2 pos) @ W1a / W1b -> hi, hj  (fp32) ----------------
__global__ void embed_hij(const float* __restrict__ c3, const float* __restrict__ gw1,
                          float* __restrict__ hi, float* __restrict__ hj) {
  int nb = blockIdx.x;               // n*64 + p
  int n = nb >> 6, p = nb & 63;
  int py = p >> 3, px = p & 7;
  int t = threadIdx.x;
  __shared__ float xf[26];
  if (t < 24)       xf[t]  = c3[((size_t)(n * 24 + t) * 8 + py) * 8 + px];
  else if (t == 24) xf[24] = -1.f + (2.f / 7.f) * px;
  else if (t == 25) xf[25] = -1.f + (2.f / 7.f) * py;
  __syncthreads();
  float a = 0.f, b = 0.f;
#pragma unroll
  for (int c = 0; c < 26; ++c) {
    float v = xf[c];
    a += v * gw1[c * 256 + t];
    b += v * gw1[(26 + c) * 256 + t];
  }
  hi[(size_t)nb * 256 + t] = a;
  hj[(size_t)nb * 256 + t] = b;
}

// ---------------- hq = qst @ W1c + g_b1 ----------------
__global__ void hq_kernel(const float* __restrict__ qst, const float* __restrict__ gw1,
                          const float* __restrict__ gb1, float* __restrict__ hq) {
  int n = blockIdx.x, t = threadIdx.x;
  __shared__ float qs[128];
  if (t < 128) qs[t] = qst[n * 128 + t];
  __syncthreads();
  float a = gb1[t];
  for (int c = 0; c < 128; ++c) a += qs[c] * gw1[(52 + c) * 256 + t];
  hq[n * 256 + t] = a;
}

// ---------------- Fused relation network: one WG per (n, i); 64 j-rows x 256 feat ----------------
__global__ void g_fused(const float* __restrict__ hi, const float* __restrict__ hj,
                        const float* __restrict__ hq, const __bf16* __restrict__ Wt,
                        const float* __restrict__ b2, const float* __restrict__ b3,
                        const float* __restrict__ b4, float* __restrict__ s_out) {
  const int nb = blockIdx.x;
  const int n = nb >> 6;
  const int tid = threadIdx.x;
  const int wave = tid >> 6, lane = tid & 63;
  const int q = lane >> 4, lr = lane & 15;

  __shared__ __align__(16) __bf16 Hs[64 * LH];

  // Per-thread slice of hi[i]+hq: c0 = (tid&63)*4 is constant over the build loop.
  const int c0 = (tid & 63) * 4;
  float4 hb4 = *(const float4*)(hi + (size_t)nb * 256 + c0);
  float4 hqv = *(const float4*)(hq + (size_t)n * 256 + c0);
  hb4.x += hqv.x; hb4.y += hqv.y; hb4.z += hqv.z; hb4.w += hqv.w;

  // Build H1 = relu(hj[j] + hi[i] + hq), bf16 into LDS
  const float* hjb = hj + (size_t)n * 64 * 256;
#pragma unroll
  for (int it = 0; it < 16; ++it) {
    int j = it * 4 + wave;
    float4 v = *(const float4*)(hjb + j * 256 + c0);
    bf16x4 o;
    o[0] = (__bf16)fmaxf(v.x + hb4.x, 0.f);
    o[1] = (__bf16)fmaxf(v.y + hb4.y, 0.f);
    o[2] = (__bf16)fmaxf(v.z + hb4.z, 0.f);
    o[3] = (__bf16)fmaxf(v.w + hb4.w, 0.f);
    *(bf16x4*)&Hs[j * LH + c0] = o;
  }
  __syncthreads();

  const int colloc = wave * 64 + lr;   // + c*16 per col-tile
  // Per-lane base into the fragment-ordered weights (fully coalesced across the wave).
  const __bf16* Bp = Wt + (size_t)wave * 2048 + lr * 32 + q * 8;

  for (int l = 0; l < 3; ++l) {
    const __bf16* Bl = Bp + (size_t)l * 65536;
    const float* bl = (l == 0) ? b2 : (l == 1) ? b3 : b4;

    f32x4 acc[4][4];
#pragma unroll
    for (int r = 0; r < 4; ++r)
#pragma unroll
      for (int c = 0; c < 4; ++c) acc[r][c] = (f32x4){0.f, 0.f, 0.f, 0.f};

#pragma unroll
    for (int ks = 0; ks < 8; ++ks) {
      bf16x8 a[4], b[4];
#pragma unroll
      for (int r = 0; r < 4; ++r)
        a[r] = *(const bf16x8*)&Hs[(r * 16 + lr) * LH + ks * 32 + q * 8];
#pragma unroll
      for (int c = 0; c < 4; ++c)
        b[c] = *(const bf16x8*)&Bl[ks * 8192 + c * 512];
#pragma unroll
      for (int r = 0; r < 4; ++r)
#pragma unroll
        for (int c = 0; c < 4; ++c)
          acc[r][c] = __builtin_amdgcn_mfma_f32_16x16x32_bf16(a[r], b[c], acc[r][c], 0, 0, 0);
    }

    float bias[4];
#pragma unroll
    for (int c = 0; c < 4; ++c) bias[c] = bl[colloc + c * 16];

    if (l < 2) {
      __syncthreads();   // all waves done reading Hs
#pragma unroll
      for (int r = 0; r < 4; ++r)
#pragma unroll
        for (int c = 0; c < 4; ++c)
#pragma unroll
          for (int reg = 0; reg < 4; ++reg) {
            int row = r * 16 + q * 4 + reg;    // C/D: row = quad*4 + reg
            Hs[row * LH + colloc + c * 16] = (__bf16)fmaxf(acc[r][c][reg] + bias[c], 0.f);
          }
      __syncthreads();
    } else {
      // final layer: relu + column-sum over all 64 rows, then atomicAdd
#pragma unroll
      for (int c = 0; c < 4; ++c) {
        float cs = 0.f;
#pragma unroll
        for (int r = 0; r < 4; ++r)
#pragma unroll
          for (int reg = 0; reg < 4; ++reg)
            cs += fmaxf(acc[r][c][reg] + bias[c], 0.f);
        cs += __shfl_xor(cs, 16);
        cs += __shfl_xor(cs, 32);
        if (q == 0) atomicAdd(&s_out[n * 256 + colloc + c * 16], cs);
      }
    }
  }
}

// ---------------- f-network + classifier + log_softmax: one WG per batch row ----------------
__global__ void f_net(const float* __restrict__ s, const float* __restrict__ fw1,
                      const float* __restrict__ fb1, const float* __restrict__ fw2,
                      const float* __restrict__ fb2, const float* __restrict__ cw,
                      const float* __restrict__ cb, float* __restrict__ out) {
  int n = blockIdx.x, t = threadIdx.x;
  __shared__ float buf[256], buf2[256], zs[32];
  buf[t] = s[n * 256 + t];
  __syncthreads();
  float a = fb1[t];
  for (int c = 0; c < 256; ++c) a += buf[c] * fw1[c * 256 + t];
  a = fmaxf(a, 0.f);
  buf2[t] = a;
  __syncthreads();
  float y = fb2[t];
  for (int c = 0; c < 256; ++c) y += buf2[c] * fw2[c * 256 + t];
  y = fmaxf(y, 0.f);
  __syncthreads();
  buf[t] = y;
  __syncthreads();
  float z = 0.f;
  if (t < 32) {
    z = cb[t];
    for (int c = 0; c < 256; ++c) z += buf[c] * cw[c * 32 + t];
    zs[t] = z;
  }
  __syncthreads();
  if (t < 32) {
    float m = -1e30f;
    for (int c = 0; c < 32; ++c) m = fmaxf(m, zs[c]);
    float se = 0.f;
    for (int c = 0; c < 32; ++c) se += expf(zs[c] - m);
    out[n * 32 + t] = z - m - logf(se);
  }
}

extern "C" void kernel_launch(void* const* d_in, const int* in_sizes, int n_in,
                              void* d_out, int out_size, void* d_ws, size_t ws_size,
                              hipStream_t stream) {
  const float* img  = (const float*)d_in[0];
  const float* qst  = (const float*)d_in[1];
  const float* w0   = (const float*)d_in[2];
  const float* w1   = (const float*)d_in[3];
  const float* w2   = (const float*)d_in[4];
  const float* w3   = (const float*)d_in[5];
  const float* bs0  = (const float*)d_in[6];
  const float* bb0  = (const float*)d_in[7];
  const float* bs1  = (const float*)d_in[8];
  const float* bb1  = (const float*)d_in[9];
  const float* bs2  = (const float*)d_in[10];
  const float* bb2  = (const float*)d_in[11];
  const float* bs3  = (const float*)d_in[12];
  const float* bb3  = (const float*)d_in[13];
  const float* gw1  = (const float*)d_in[14];
  const float* gb1  = (const float*)d_in[15];
  const float* gw2  = (const float*)d_in[16];
  const float* gb2  = (const float*)d_in[17];
  const float* gw3  = (const float*)d_in[18];
  const float* gb3  = (const float*)d_in[19];
  const float* gw4  = (const float*)d_in[20];
  const float* gb4  = (const float*)d_in[21];
  const float* fw1  = (const float*)d_in[22];
  const float* fb1  = (const float*)d_in[23];
  const float* fw2  = (const float*)d_in[24];
  const float* fb2  = (const float*)d_in[25];
  const float* cw   = (const float*)d_in[26];
  const float* cb   = (const float*)d_in[27];

  char* ws = (char*)d_ws;
  // conv activations
  float* c0 = (float*)(ws + 0);                    // 25,165,824 B
  float* c1 = (float*)(ws + 25165824);             //  6,291,456 B
  float* c2 = (float*)(ws + 31457280);             //  1,572,864 B
  float* c3 = (float*)(ws + 33030144);             //    393,216 B
  // reuse c0 region after conv1 consumed it (stream-ordered):
  float*  hi = (float*)(ws + 0);                   // 4,194,304 B
  float*  hj = (float*)(ws + 4194304);             // 4,194,304 B
  float*  hqb = (float*)(ws + 8388608);            //    65,536 B
  float*  sbuf = (float*)(ws + 8454144);           //    65,536 B
  __bf16* Wt = (__bf16*)(ws + 8519680);            //   393,216 B

  conv_bn_relu<3, true><<<1024, 256, 0, stream>>>(img, w0, bs0, bb0, c0, 64, 128, 128);
  conv_bn_relu<24, true><<<256, 256, 0, stream>>>(c0, w1, bs1, bb1, c1, 64, 64, 64);
  conv_bn_relu<24, false><<<256, 64, 0, stream>>>(c1, w2, bs2, bb2, c2, 64, 32, 32);
  conv_bn_relu<24, false><<<64, 64, 0, stream>>>(c2, w3, bs3, bb3, c3, 64, 16, 16);

  wt_frag<<<24, 256, 0, stream>>>(gw2, gw3, gw4, Wt);
  embed_hij<<<4096, 256, 0, stream>>>(c3, gw1, hi, hj);
  hq_kernel<<<64, 256, 0, stream>>>(qst, gw1, gb1, hqb);

  hipMemsetAsync(sbuf, 0, 64 * 256 * sizeof(float), stream);
  g_fused<<<4096, 256, 0, stream>>>(hi, hj, hqb, Wt, gb2, gb3, gb4, sbuf);
  f_net<<<64, 256, 0, stream>>>(sbuf, fw1, fb1, fw2, fb2, cw, cb, (float*)d_out);
}

// Round 3
// 427.704 us; speedup vs baseline: 1.2572x; 1.1390x over previous
//
#include <hip/hip_runtime.h>
#include <hip/hip_bf16.h>
#include <math.h>

typedef __bf16 bf16x8 __attribute__((ext_vector_type(8)));
typedef __bf16 bf16x4 __attribute__((ext_vector_type(4)));
typedef float  f32x4  __attribute__((ext_vector_type(4)));

#define LH 264   // Hs row stride in bf16 elems (528 B): 16B-aligned, breaks pow2 bank aliasing

// ---------------- Conv 3x3 stride2 pad1 + BN + ReLU, 2 output positions/thread ----------------
// Weights staged in LDS; each thread computes 24 channels x 2 adjacent ox. The 7-wide input
// window is shared across kx and both positions -> 144 FMA per 6 ds_read_b128 (VALU-bound).
template<int CIN>
__global__ void conv_bn_relu2(const float* __restrict__ x, const float* __restrict__ w,
                              const float* __restrict__ sc, const float* __restrict__ bi,
                              float* __restrict__ y, int N, int H, int W) {
  const int OH = H >> 1, OW = W >> 1, OW2 = OW >> 1;
  __shared__ float wl[9 * CIN * 24];
  for (int i = threadIdx.x; i < 9 * CIN * 24; i += blockDim.x) wl[i] = w[i];
  __syncthreads();

  int idx = blockIdx.x * blockDim.x + threadIdx.x;
  int total = N * OH * OW2;
  if (idx >= total) return;
  int oxh = idx % OW2; int t = idx / OW2; int oy = t % OH; int n = t / OH;
  int ox0 = oxh * 2;

  float acc0[24], acc1[24];
#pragma unroll
  for (int co = 0; co < 24; ++co) { acc0[co] = 0.f; acc1[co] = 0.f; }

  for (int ci = 0; ci < CIN; ++ci) {
    const float* xp = x + (size_t)(n * CIN + ci) * H * W;
#pragma unroll
    for (int ky = 0; ky < 3; ++ky) {
      int iy = 2 * oy + ky - 1;
      if (iy < 0 || iy >= H) continue;
      const float* row = xp + (size_t)iy * W;
      int ixb = 2 * ox0 - 1;
      float in[7];
#pragma unroll
      for (int u = 0; u < 7; ++u) {
        int ix = ixb + u;
        in[u] = (ix >= 0 && ix < W) ? row[ix] : 0.f;
      }
#pragma unroll
      for (int kx = 0; kx < 3; ++kx) {
        const float* wp = &wl[((ky * 3 + kx) * CIN + ci) * 24];
        float v0 = in[kx], v1 = in[kx + 2];
#pragma unroll
        for (int co = 0; co < 24; ++co) {
          float wv = wp[co];
          acc0[co] += v0 * wv;
          acc1[co] += v1 * wv;
        }
      }
    }
  }
  float* yp = y + (size_t)n * 24 * OH * OW + (size_t)oy * OW + ox0;
#pragma unroll
  for (int co = 0; co < 24; ++co) {
    float s = sc[co], b = bi[co];
    yp[(size_t)co * OH * OW]     = fmaxf(acc0[co] * s + b, 0.f);
    yp[(size_t)co * OH * OW + 1] = fmaxf(acc1[co] * s + b, 0.f);
  }
}

// ---------------- Conv 3x3 stride2 pad1 + BN + ReLU, 1 position/thread (small grids) ---------
template<int CIN>
__global__ void conv_bn_relu(const float* __restrict__ x, const float* __restrict__ w,
                             const float* __restrict__ sc, const float* __restrict__ bi,
                             float* __restrict__ y, int N, int H, int W) {
  const int OH = H >> 1, OW = W >> 1;
  __shared__ float wl[9 * CIN * 24];
  for (int i = threadIdx.x; i < 9 * CIN * 24; i += blockDim.x) wl[i] = w[i];
  __syncthreads();

  int idx = blockIdx.x * blockDim.x + threadIdx.x;
  int total = N * OH * OW;
  if (idx >= total) return;
  int ox = idx % OW; int t = idx / OW; int oy = t % OH; int n = t / OH;

  float acc[24];
#pragma unroll
  for (int co = 0; co < 24; ++co) acc[co] = 0.f;

  for (int ci = 0; ci < CIN; ++ci) {
    const float* xp = x + (size_t)(n * CIN + ci) * H * W;
#pragma unroll
    for (int ky = 0; ky < 3; ++ky) {
      int iy = 2 * oy + ky - 1;
      if (iy < 0 || iy >= H) continue;
#pragma unroll
      for (int kx = 0; kx < 3; ++kx) {
        int ix = 2 * ox + kx - 1;
        if (ix < 0 || ix >= W) continue;
        float v = xp[(size_t)iy * W + ix];
        const float* wp = &wl[((ky * 3 + kx) * CIN + ci) * 24];
#pragma unroll
        for (int co = 0; co < 24; ++co) acc[co] += v * wp[co];
      }
    }
  }
  float* yp = y + (size_t)n * 24 * OH * OW + (size_t)oy * OW + ox;
#pragma unroll
  for (int co = 0; co < 24; ++co)
    yp[(size_t)co * OH * OW] = fmaxf(acc[co] * sc[co] + bi[co], 0.f);
}

// ---------------- g_w2/3/4 (256x256 fp32 [k][n]) -> Wfrag bf16 in MFMA-B-fragment order -----
// elem((l, ks, n, q, j)) at ((l*8+ks)*256 + n)*32 + q*8 + j holds src[k=ks*32+q*8+j][n].
__global__ void wt_frag(const float* __restrict__ g2, const float* __restrict__ g3,
                        const float* __restrict__ g4, __bf16* __restrict__ Wt) {
  int l = blockIdx.x >> 3, ks = blockIdx.x & 7;
  const float* src = (l == 0) ? g2 : (l == 1) ? g3 : g4;
  __shared__ float tile[32][257];
  int t = threadIdx.x;
  for (int kk = 0; kk < 32; ++kk) tile[kk][t] = src[(ks * 32 + kk) * 256 + t];
  __syncthreads();
  int q = t & 3, nb = t >> 2;
  __bf16* out = Wt + (size_t)(l * 8 + ks) * 8192;
#pragma unroll
  for (int i = 0; i < 4; ++i) {
    int n = i * 64 + nb;
    bf16x8 v;
#pragma unroll
    for (int j = 0; j < 8; ++j) v[j] = (__bf16)tile[q * 8 + j][n];
    *(bf16x8*)&out[n * 32 + q * 8] = v;
  }
}

// ---------------- x_feat (24 conv ch + 2 pos) @ W1a / W1b -> hi, hj  (fp32) ----------------
__global__ void embed_hij(const float* __restrict__ c3, const float* __restrict__ gw1,
                          float* __restrict__ hi, float* __restrict__ hj) {
  int nb = blockIdx.x;               // n*64 + p
  int n = nb >> 6, p = nb & 63;
  int py = p >> 3, px = p & 7;
  int t = threadIdx.x;
  __shared__ float xf[26];
  if (t < 24)       xf[t]  = c3[((size_t)(n * 24 + t) * 8 + py) * 8 + px];
  else if (t == 24) xf[24] = -1.f + (2.f / 7.f) * px;
  else if (t == 25) xf[25] = -1.f + (2.f / 7.f) * py;
  __syncthreads();
  float a = 0.f, b = 0.f;
#pragma unroll
  for (int c = 0; c < 26; ++c) {
    float v = xf[c];
    a += v * gw1[c * 256 + t];
    b += v * gw1[(26 + c) * 256 + t];
  }
  hi[(size_t)nb * 256 + t] = a;
  hj[(size_t)nb * 256 + t] = b;
}

// ---------------- hq = qst @ W1c + g_b1 ----------------
__global__ void hq_kernel(const float* __restrict__ qst, const float* __restrict__ gw1,
                          const float* __restrict__ gb1, float* __restrict__ hq) {
  int n = blockIdx.x, t = threadIdx.x;
  __shared__ float qs[128];
  if (t < 128) qs[t] = qst[n * 128 + t];
  __syncthreads();
  float a = gb1[t];
  for (int c = 0; c < 128; ++c) a += qs[c] * gw1[(52 + c) * 256 + t];
  hq[n * 256 + t] = a;
}

// ---------------- Fused relation network: one WG per (n, i-pair); M=128 rows x 256 feat ------
// Two i-values share the same weight fragments: halves L2 weight traffic, doubles MFMA density.
__global__ __launch_bounds__(256, 2)
void g_fused(const float* __restrict__ hi, const float* __restrict__ hj,
             const float* __restrict__ hq, const __bf16* __restrict__ Wt,
             const float* __restrict__ b2, const float* __restrict__ b3,
             const float* __restrict__ b4, float* __restrict__ s_out) {
  const int blk = blockIdx.x;          // n*32 + ib ; i = 2*ib, 2*ib+1
  const int n = blk >> 5, ib = blk & 31;
  const int tid = threadIdx.x;
  const int wave = tid >> 6, lane = tid & 63;
  const int q = lane >> 4, lr = lane & 15;

  __shared__ __align__(16) __bf16 Hs[128 * LH];

  const int c0 = (tid & 63) * 4;
  float4 hq4 = *(const float4*)(hq + (size_t)n * 256 + c0);
  float4 h0 = *(const float4*)(hi + (size_t)(n * 64 + ib * 2)     * 256 + c0);
  float4 h1 = *(const float4*)(hi + (size_t)(n * 64 + ib * 2 + 1) * 256 + c0);
  h0.x += hq4.x; h0.y += hq4.y; h0.z += hq4.z; h0.w += hq4.w;
  h1.x += hq4.x; h1.y += hq4.y; h1.z += hq4.z; h1.w += hq4.w;

  // Build H1 = relu(hj[j] + hi[i] + hq), bf16 into LDS: rows 0..63 -> i0, 64..127 -> i1
  const float* hjb = hj + (size_t)n * 64 * 256;
#pragma unroll
  for (int it = 0; it < 16; ++it) {
    int j = it * 4 + wave;
    float4 v = *(const float4*)(hjb + j * 256 + c0);
    bf16x4 o;
    o[0] = (__bf16)fmaxf(v.x + h0.x, 0.f);
    o[1] = (__bf16)fmaxf(v.y + h0.y, 0.f);
    o[2] = (__bf16)fmaxf(v.z + h0.z, 0.f);
    o[3] = (__bf16)fmaxf(v.w + h0.w, 0.f);
    *(bf16x4*)&Hs[j * LH + c0] = o;
    bf16x4 o2;
    o2[0] = (__bf16)fmaxf(v.x + h1.x, 0.f);
    o2[1] = (__bf16)fmaxf(v.y + h1.y, 0.f);
    o2[2] = (__bf16)fmaxf(v.z + h1.z, 0.f);
    o2[3] = (__bf16)fmaxf(v.w + h1.w, 0.f);
    *(bf16x4*)&Hs[(64 + j) * LH + c0] = o2;
  }
  __syncthreads();

  const int colloc = wave * 64 + lr;   // + c*16 per col-tile
  const __bf16* Bp = Wt + (size_t)wave * 2048 + lr * 32 + q * 8;

  for (int l = 0; l < 3; ++l) {
    const __bf16* Bl = Bp + (size_t)l * 65536;
    const float* bl = (l == 0) ? b2 : (l == 1) ? b3 : b4;

    f32x4 acc[8][4];
#pragma unroll
    for (int r = 0; r < 8; ++r)
#pragma unroll
      for (int c = 0; c < 4; ++c) acc[r][c] = (f32x4){0.f, 0.f, 0.f, 0.f};

    for (int ks = 0; ks < 8; ++ks) {
      bf16x8 b[4];
#pragma unroll
      for (int c = 0; c < 4; ++c)
        b[c] = *(const bf16x8*)&Bl[ks * 8192 + c * 512];
      bf16x8 a[8];
#pragma unroll
      for (int r = 0; r < 8; ++r)
        a[r] = *(const bf16x8*)&Hs[(r * 16 + lr) * LH + ks * 32 + q * 8];
#pragma unroll
      for (int r = 0; r < 8; ++r)
#pragma unroll
        for (int c = 0; c < 4; ++c)
          acc[r][c] = __builtin_amdgcn_mfma_f32_16x16x32_bf16(a[r], b[c], acc[r][c], 0, 0, 0);
    }

    float bias[4];
#pragma unroll
    for (int c = 0; c < 4; ++c) bias[c] = bl[colloc + c * 16];

    if (l < 2) {
      __syncthreads();   // all waves done reading Hs
#pragma unroll
      for (int r = 0; r < 8; ++r)
#pragma unroll
        for (int c = 0; c < 4; ++c)
#pragma unroll
          for (int reg = 0; reg < 4; ++reg) {
            int row = r * 16 + q * 4 + reg;    // C/D: row = quad*4 + reg
            Hs[row * LH + colloc + c * 16] = (__bf16)fmaxf(acc[r][c][reg] + bias[c], 0.f);
          }
      __syncthreads();
    } else {
      // final layer: relu + column-sum over all 128 rows, then atomicAdd
#pragma unroll
      for (int c = 0; c < 4; ++c) {
        float cs = 0.f;
#pragma unroll
        for (int r = 0; r < 8; ++r)
#pragma unroll
          for (int reg = 0; reg < 4; ++reg)
            cs += fmaxf(acc[r][c][reg] + bias[c], 0.f);
        cs += __shfl_xor(cs, 16);
        cs += __shfl_xor(cs, 32);
        if (q == 0) atomicAdd(&s_out[n * 256 + colloc + c * 16], cs);
      }
    }
  }
}

// ---------------- f-network + classifier + log_softmax: one WG per batch row ----------------
__global__ void f_net(const float* __restrict__ s, const float* __restrict__ fw1,
                      const float* __restrict__ fb1, const float* __restrict__ fw2,
                      const float* __restrict__ fb2, const float* __restrict__ cw,
                      const float* __restrict__ cb, float* __restrict__ out) {
  int n = blockIdx.x, t = threadIdx.x;
  __shared__ float buf[256], buf2[256], zs[32];
  buf[t] = s[n * 256 + t];
  __syncthreads();
  float a = fb1[t];
  for (int c = 0; c < 256; ++c) a += buf[c] * fw1[c * 256 + t];
  a = fmaxf(a, 0.f);
  buf2[t] = a;
  __syncthreads();
  float y = fb2[t];
  for (int c = 0; c < 256; ++c) y += buf2[c] * fw2[c * 256 + t];
  y = fmaxf(y, 0.f);
  __syncthreads();
  buf[t] = y;
  __syncthreads();
  float z = 0.f;
  if (t < 32) {
    z = cb[t];
    for (int c = 0; c < 256; ++c) z += buf[c] * cw[c * 32 + t];
    zs[t] = z;
  }
  __syncthreads();
  if (t < 32) {
    float m = -1e30f;
    for (int c = 0; c < 32; ++c) m = fmaxf(m, zs[c]);
    float se = 0.f;
    for (int c = 0; c < 32; ++c) se += expf(zs[c] - m);
    out[n * 32 + t] = z - m - logf(se);
  }
}

extern "C" void kernel_launch(void* const* d_in, const int* in_sizes, int n_in,
                              void* d_out, int out_size, void* d_ws, size_t ws_size,
                              hipStream_t stream) {
  const float* img  = (const float*)d_in[0];
  const float* qst  = (const float*)d_in[1];
  const float* w0   = (const float*)d_in[2];
  const float* w1   = (const float*)d_in[3];
  const float* w2   = (const float*)d_in[4];
  const float* w3   = (const float*)d_in[5];
  const float* bs0  = (const float*)d_in[6];
  const float* bb0  = (const float*)d_in[7];
  const float* bs1  = (const float*)d_in[8];
  const float* bb1  = (const float*)d_in[9];
  const float* bs2  = (const float*)d_in[10];
  const float* bb2  = (const float*)d_in[11];
  const float* bs3  = (const float*)d_in[12];
  const float* bb3  = (const float*)d_in[13];
  const float* gw1  = (const float*)d_in[14];
  const float* gb1  = (const float*)d_in[15];
  const float* gw2  = (const float*)d_in[16];
  const float* gb2  = (const float*)d_in[17];
  const float* gw3  = (const float*)d_in[18];
  const float* gb3  = (const float*)d_in[19];
  const float* gw4  = (const float*)d_in[20];
  const float* gb4  = (const float*)d_in[21];
  const float* fw1  = (const float*)d_in[22];
  const float* fb1  = (const float*)d_in[23];
  const float* fw2  = (const float*)d_in[24];
  const float* fb2  = (const float*)d_in[25];
  const float* cw   = (const float*)d_in[26];
  const float* cb   = (const float*)d_in[27];

  char* ws = (char*)d_ws;
  // conv activations
  float* c0 = (float*)(ws + 0);                    // 25,165,824 B
  float* c1 = (float*)(ws + 25165824);             //  6,291,456 B
  float* c2 = (float*)(ws + 31457280);             //  1,572,864 B
  float* c3 = (float*)(ws + 33030144);             //    393,216 B
  // reuse c0 region after conv1 consumed it (stream-ordered):
  float*  hi = (float*)(ws + 0);                   // 4,194,304 B
  float*  hj = (float*)(ws + 4194304);             // 4,194,304 B
  float*  hqb = (float*)(ws + 8388608);            //    65,536 B
  float*  sbuf = (float*)(ws + 8454144);           //    65,536 B
  __bf16* Wt = (__bf16*)(ws + 8519680);            //   393,216 B

  conv_bn_relu2<3><<<512, 256, 0, stream>>>(img, w0, bs0, bb0, c0, 64, 128, 128);
  conv_bn_relu2<24><<<128, 256, 0, stream>>>(c0, w1, bs1, bb1, c1, 64, 64, 64);
  conv_bn_relu<24><<<64, 256, 0, stream>>>(c1, w2, bs2, bb2, c2, 64, 32, 32);
  conv_bn_relu<24><<<16, 256, 0, stream>>>(c2, w3, bs3, bb3, c3, 64, 16, 16);

  wt_frag<<<24, 256, 0, stream>>>(gw2, gw3, gw4, Wt);
  embed_hij<<<4096, 256, 0, stream>>>(c3, gw1, hi, hj);
  hq_kernel<<<64, 256, 0, stream>>>(qst, gw1, gb1, hqb);

  hipMemsetAsync(sbuf, 0, 64 * 256 * sizeof(float), stream);
  g_fused<<<2048, 256, 0, stream>>>(hi, hj, hqb, Wt, gb2, gb3, gb4, sbuf);
  f_net<<<64, 256, 0, stream>>>(sbuf, fw1, fb1, fw2, fb2, cw, cb, (float*)d_out);
}